// Round 1
// baseline (595.691 us; speedup 1.0000x reference)
//
#include <hip/hip_runtime.h>
#include <hip/hip_bf16.h>

typedef __attribute__((ext_vector_type(8))) short short8;
typedef __attribute__((ext_vector_type(4))) float f32x4;

#define B_    8
#define N_    4097
#define C_    768
#define H_    12
#define HD_   64
#define M_TOT (B_*N_)      /* 32776 */
#define K3    (3*C_)       /* 2304  */
#define CHUNKS 16

__device__ __forceinline__ float bf2f(unsigned short u) {
  union { unsigned int i; float f; } x; x.i = ((unsigned int)u) << 16; return x.f;
}
__device__ __forceinline__ unsigned short f2bf(float f) {
  union { float f; unsigned int i; } x; x.f = f;
  unsigned int i = x.i + 0x7fffu + ((x.i >> 16) & 1u);
  return (unsigned short)(i >> 16);
}

__device__ __forceinline__ void gload16(const void* g, void* l) {
  __builtin_amdgcn_global_load_lds(
      (const __attribute__((address_space(1))) void*)g,
      (__attribute__((address_space(3))) void*)l, 16, 0, 0);
}

// ---------------- fp32 -> bf16 convert (x and qkv_w) ----------------
__global__ __launch_bounds__(256) void cvt_kernel(const float* __restrict__ in,
                                                  unsigned short* __restrict__ out,
                                                  long n4) {
  long i = (long)blockIdx.x * blockDim.x + threadIdx.x;
  long stride = (long)gridDim.x * blockDim.x;
  for (; i < n4; i += stride) {
    float4 v = ((const float4*)in)[i];
    ushort4 o;
    o.x = f2bf(v.x); o.y = f2bf(v.y); o.z = f2bf(v.z); o.w = f2bf(v.w);
    ((ushort4*)out)[i] = o;
  }
}

// ---------------- GEMM1: qkv = x @ qkv_w^T, fused bias + RoPE ----------------
// A = x_bf16 [32776,768], B = wq_bf16 [2304,768] (bt layout), out qkv bf16 [32776,2304]
__global__ __launch_bounds__(256) void gemm_qkv_rope(
    const unsigned short* __restrict__ A,
    const unsigned short* __restrict__ Bw,
    const float* __restrict__ rope,   // [4096,128] sin||cos
    const float* __restrict__ qb,
    const float* __restrict__ vb,
    unsigned short* __restrict__ qkv)
{
  __shared__ unsigned short Al[128*32];
  __shared__ unsigned short Bl[128*32];
  const int t    = threadIdx.x;
  const int wave = t >> 6, lane = t & 63;
  const int m0 = blockIdx.y * 128;
  const int n0 = blockIdx.x * 128;
  const int wr = wave >> 1, wc = wave & 1;
  const int lr = lane & 15, lk = lane >> 4;

  f32x4 acc[4][4];
#pragma unroll
  for (int i = 0; i < 4; ++i)
#pragma unroll
    for (int j = 0; j < 4; ++j) acc[i][j] = (f32x4){0.f,0.f,0.f,0.f};

  const int so0 = (wave*2 + 0) * 1024;   // byte offset in 8KB tile
  const int so1 = (wave*2 + 1) * 1024;
  const int f0 = so0 + lane*16, f1 = so1 + lane*16;
  const int r0 = f0 >> 6, cb0 = f0 & 63;
  const int r1 = f1 >> 6, cb1 = f1 & 63;
  int am0 = m0 + r0; if (am0 > M_TOT-1) am0 = M_TOT-1;
  int am1 = m0 + r1; if (am1 > M_TOT-1) am1 = M_TOT-1;
  const unsigned short* a0 = A + (long)am0*768 + (cb0 >> 1);
  const unsigned short* a1 = A + (long)am1*768 + (cb1 >> 1);
  const unsigned short* b0 = Bw + (long)(n0 + r0)*768 + (cb0 >> 1);
  const unsigned short* b1 = Bw + (long)(n0 + r1)*768 + (cb1 >> 1);

  for (int kk = 0; kk < 768; kk += 32) {
    __syncthreads();
    gload16(a0 + kk, (char*)Al + so0);
    gload16(a1 + kk, (char*)Al + so1);
    gload16(b0 + kk, (char*)Bl + so0);
    gload16(b1 + kk, (char*)Bl + so1);
    __syncthreads();
    short8 af[4], bfr[4];
#pragma unroll
    for (int mi = 0; mi < 4; ++mi)
      af[mi] = *(const short8*)(Al + (wr*64 + mi*16 + lr)*32 + lk*8);
#pragma unroll
    for (int ni = 0; ni < 4; ++ni)
      bfr[ni] = *(const short8*)(Bl + (wc*64 + ni*16 + lr)*32 + lk*8);
#pragma unroll
    for (int mi = 0; mi < 4; ++mi)
#pragma unroll
      for (int ni = 0; ni < 4; ++ni)
        acc[mi][ni] = __builtin_amdgcn_mfma_f32_16x16x32_bf16(af[mi], bfr[ni], acc[mi][ni], 0, 0, 0);
  }

  const int which = n0 / 768;  // 0=q,1=k,2=v (block-uniform: 768 % 128 == 0)
#pragma unroll
  for (int mi = 0; mi < 4; ++mi) {
#pragma unroll
    for (int ni = 0; ni < 4; ++ni) {
      const int gc = n0 + wc*64 + ni*16 + lr;
      const int within = gc - which*768;
      const int d = within & 63;
      float bias = 0.f;
      if (which == 0) bias = qb[within];
      else if (which == 2) bias = vb[within];
#pragma unroll
      for (int r = 0; r < 4; ++r) {
        const int gm = m0 + wr*64 + mi*16 + lk*4 + r;
        float v = acc[mi][ni][r] + bias;
        float pair = __shfl_xor(v, 1);   // col d^1 lives in lane^1
        float vo = v;
        if (which < 2) {
          const int ntok = gm % 4097;
          if (ntok > 0 && gm < M_TOT) {
            const float* rp = rope + (long)(ntok - 1)*128 + d;
            const float s = rp[0], c = rp[64];
            const float rot = (d & 1) ? pair : -pair;
            vo = v*c + rot*s;
          }
        }
        if (gm < M_TOT) qkv[(long)gm*K3 + gc] = f2bf(vo);
      }
    }
  }
}

// ---------------- kv partials: kv[b,h] = K^T V over an N-chunk ----------------
__global__ __launch_bounds__(256) void kv_partial_kernel(
    const unsigned short* __restrict__ qkv, float* __restrict__ part)
{
  const int bh = blockIdx.y;            // 0..95
  const int b = bh / 12, h = bh % 12;
  const int chunk = blockIdx.x;         // 0..15
  const int per = (N_ + CHUNKS - 1) / CHUNKS;  // 257
  const int nst = chunk * per;
  const int nen = min(nst + per, N_);
  __shared__ unsigned short Kl[32*64];
  __shared__ unsigned short Vl[32*64];
  const int t = threadIdx.x;
  const int ty = t >> 4, tx = t & 15;
  const int lrow = t >> 3, lpc = t & 7;
  float acc[4][4] = {};
  for (int nb = nst; nb < nen; nb += 32) {
    const int cnt = min(32, nen - nb);
    __syncthreads();
    if (lrow < cnt) {
      const unsigned short* src = qkv + ((long)b*N_ + nb + lrow)*K3;
      *(uint4*)(Kl + lrow*64 + lpc*8) = *(const uint4*)(src + 768  + h*64 + lpc*8);
      *(uint4*)(Vl + lrow*64 + lpc*8) = *(const uint4*)(src + 1536 + h*64 + lpc*8);
    }
    __syncthreads();
    for (int i = 0; i < cnt; ++i) {
      const ushort4 ku = *(const ushort4*)(Kl + i*64 + ty*4);
      const ushort4 vu = *(const ushort4*)(Vl + i*64 + tx*4);
      float kf[4] = {bf2f(ku.x), bf2f(ku.y), bf2f(ku.z), bf2f(ku.w)};
      float vf[4] = {bf2f(vu.x), bf2f(vu.y), bf2f(vu.z), bf2f(vu.w)};
#pragma unroll
      for (int a = 0; a < 4; ++a)
#pragma unroll
        for (int e = 0; e < 4; ++e) acc[a][e] += kf[a]*vf[e];
    }
  }
  float* dst = part + ((long)chunk*96 + bh)*4096 + (ty*4)*64 + tx*4;
#pragma unroll
  for (int a = 0; a < 4; ++a)
#pragma unroll
    for (int e = 0; e < 4; ++e) dst[a*64 + e] = acc[a][e];
}

__global__ __launch_bounds__(256) void kv_reduce_kernel(const float* __restrict__ part,
                                                        float* __restrict__ kvf) {
  const int i = blockIdx.x*256 + threadIdx.x;  // 96*4096 = 393216
  float s = 0.f;
#pragma unroll
  for (int c = 0; c < CHUNKS; ++c) s += part[(long)c*96*4096 + i];
  kvf[i] = s;
}

// ---------------- McombT[b][c][h*64+d] = sum_e kv[b,h,d,e]*proj_w[c,h*64+e] / (hd*N) --------
__global__ __launch_bounds__(256) void mcomb_kernel(const float* __restrict__ kvf,
                                                    const float* __restrict__ pw,
                                                    unsigned short* __restrict__ McT) {
  const long o = (long)blockIdx.x*256 + threadIdx.x;   // < 8*768*768
  const int j = (int)(o % 768);
  const long t2 = o / 768;
  const int c = (int)(t2 % 768);
  const int b = (int)(t2 / 768);
  const int h = j >> 6, d = j & 63;
  const float* kvp = kvf + ((long)(b*12 + h)*64 + d)*64;
  const float* pwp = pw + (long)c*768 + h*64;
  float s = 0.f;
#pragma unroll 8
  for (int e = 0; e < 64; ++e) s += kvp[e]*pwp[e];
  McT[o] = f2bf(s * (float)(1.0/(64.0*4097.0)));
}

// ---------------- GEMM2: out[b] = Q[b] @ McT[b]^T + proj_b (fp32 out) ----------------
__global__ __launch_bounds__(256) void gemm_final(
    const unsigned short* __restrict__ qkv,   // Q = cols [0,768) of [32776,2304]
    const unsigned short* __restrict__ McT,   // [8,768,768] bf16
    const float* __restrict__ pb,
    float* __restrict__ out)
{
  __shared__ unsigned short Al[128*32];
  __shared__ unsigned short Bl[128*32];
  const int t    = threadIdx.x;
  const int wave = t >> 6, lane = t & 63;
  const int bt = blockIdx.y;                 // 0..263
  const int b = bt / 33, rt = bt % 33;
  const int n0 = rt * 128;                   // token tile start
  const int c0 = blockIdx.x * 128;
  const int wr = wave >> 1, wc = wave & 1;
  const int lr = lane & 15, lk = lane >> 4;

  f32x4 acc[4][4];
#pragma unroll
  for (int i = 0; i < 4; ++i)
#pragma unroll
    for (int j = 0; j < 4; ++j) acc[i][j] = (f32x4){0.f,0.f,0.f,0.f};

  const int so0 = (wave*2 + 0) * 1024;
  const int so1 = (wave*2 + 1) * 1024;
  const int f0 = so0 + lane*16, f1 = so1 + lane*16;
  const int r0 = f0 >> 6, cb0 = f0 & 63;
  const int r1 = f1 >> 6, cb1 = f1 & 63;
  int tk0 = n0 + r0; if (tk0 > N_-1) tk0 = N_-1;
  int tk1 = n0 + r1; if (tk1 > N_-1) tk1 = N_-1;
  const unsigned short* a0 = qkv + ((long)b*N_ + tk0)*K3 + (cb0 >> 1);
  const unsigned short* a1 = qkv + ((long)b*N_ + tk1)*K3 + (cb1 >> 1);
  const unsigned short* Bb = McT + (long)b*768*768;
  const unsigned short* b0 = Bb + (long)(c0 + r0)*768 + (cb0 >> 1);
  const unsigned short* b1 = Bb + (long)(c0 + r1)*768 + (cb1 >> 1);

  for (int kk = 0; kk < 768; kk += 32) {
    __syncthreads();
    gload16(a0 + kk, (char*)Al + so0);
    gload16(a1 + kk, (char*)Al + so1);
    gload16(b0 + kk, (char*)Bl + so0);
    gload16(b1 + kk, (char*)Bl + so1);
    __syncthreads();
    short8 af[4], bfr[4];
#pragma unroll
    for (int mi = 0; mi < 4; ++mi)
      af[mi] = *(const short8*)(Al + (wr*64 + mi*16 + lr)*32 + lk*8);
#pragma unroll
    for (int ni = 0; ni < 4; ++ni)
      bfr[ni] = *(const short8*)(Bl + (wc*64 + ni*16 + lr)*32 + lk*8);
#pragma unroll
    for (int mi = 0; mi < 4; ++mi)
#pragma unroll
      for (int ni = 0; ni < 4; ++ni)
        acc[mi][ni] = __builtin_amdgcn_mfma_f32_16x16x32_bf16(af[mi], bfr[ni], acc[mi][ni], 0, 0, 0);
  }

#pragma unroll
  for (int mi = 0; mi < 4; ++mi) {
#pragma unroll
    for (int ni = 0; ni < 4; ++ni) {
      const int gc = c0 + wc*64 + ni*16 + lr;
      const float bias = pb[gc];
#pragma unroll
      for (int r = 0; r < 4; ++r) {
        const int tok = n0 + wr*64 + mi*16 + lk*4 + r;
        if (tok < N_)
          out[((long)b*N_ + tok)*768 + gc] = acc[mi][ni][r] + bias;
      }
    }
  }
}

extern "C" void kernel_launch(void* const* d_in, const int* in_sizes, int n_in,
                              void* d_out, int out_size, void* d_ws, size_t ws_size,
                              hipStream_t stream) {
  const float* x      = (const float*)d_in[0];
  const float* rope   = (const float*)d_in[1];
  const float* qkv_w  = (const float*)d_in[2];
  const float* q_bias = (const float*)d_in[3];
  const float* v_bias = (const float*)d_in[4];
  const float* proj_w = (const float*)d_in[5];
  const float* proj_b = (const float*)d_in[6];
  float* out = (float*)d_out;

  // workspace layout (region0 reused: x_bf dead after gemm1)
  char* w0 = (char*)d_ws;
  unsigned short* x_bf  = (unsigned short*)w0;                        // 50,343,936 B
  unsigned short* wq_bf = (unsigned short*)(w0 + 50343936);           //  3,538,944 B
  unsigned short* qkv   = (unsigned short*)(w0 + 50343936 + 3538944); // 151,031,808 B
  float*          part  = (float*)w0;                                 // 25,165,824 B (aliases x_bf)
  float*          kvf   = (float*)(w0 + 25165824);                    //  1,572,864 B
  unsigned short* McT   = (unsigned short*)(w0 + 25165824 + 1572864); //  9,437,184 B

  cvt_kernel<<<2048, 256, 0, stream>>>(x, x_bf, (long)M_TOT*768/4);
  cvt_kernel<<<1728, 256, 0, stream>>>(qkv_w, wq_bf, (long)K3*768/4);

  gemm_qkv_rope<<<dim3(18, 257), 256, 0, stream>>>(x_bf, wq_bf, rope, q_bias, v_bias, qkv);

  kv_partial_kernel<<<dim3(CHUNKS, 96), 256, 0, stream>>>(qkv, part);
  kv_reduce_kernel<<<1536, 256, 0, stream>>>(part, kvf);
  mcomb_kernel<<<18432, 256, 0, stream>>>(kvf, proj_w, McT);

  gemm_final<<<dim3(6, 264), 256, 0, stream>>>(qkv, McT, proj_b, out);
}

// Round 2
// 558.538 us; speedup vs baseline: 1.0665x; 1.0665x over previous
//
#include <hip/hip_runtime.h>
#include <hip/hip_bf16.h>

typedef __attribute__((ext_vector_type(8))) short short8;
typedef __attribute__((ext_vector_type(4))) float f32x4;

#define B_    8
#define N_    4097
#define C_    768
#define H_    12
#define HD_   64
#define M_TOT (B_*N_)      /* 32776 */
#define K3    (3*C_)       /* 2304  */
#define CHUNKS 16
#define NT    24           /* 768/32 K-steps */

__device__ __forceinline__ float bf2f(unsigned short u) {
  union { unsigned int i; float f; } x; x.i = ((unsigned int)u) << 16; return x.f;
}
__device__ __forceinline__ unsigned short f2bf(float f) {
  union { float f; unsigned int i; } x; x.f = f;
  unsigned int i = x.i + 0x7fffu + ((x.i >> 16) & 1u);
  return (unsigned short)(i >> 16);
}

__device__ __forceinline__ void gload16(const void* g, void* l) {
  __builtin_amdgcn_global_load_lds(
      (const __attribute__((address_space(1))) void*)g,
      (__attribute__((address_space(3))) void*)l, 16, 0, 0);
}

// ---------------- fp32 -> bf16 convert (x and qkv_w) ----------------
__global__ __launch_bounds__(256) void cvt_kernel(const float* __restrict__ in,
                                                  unsigned short* __restrict__ out,
                                                  long n4) {
  long i = (long)blockIdx.x * blockDim.x + threadIdx.x;
  long stride = (long)gridDim.x * blockDim.x;
  for (; i < n4; i += stride) {
    float4 v = ((const float4*)in)[i];
    ushort4 o;
    o.x = f2bf(v.x); o.y = f2bf(v.y); o.z = f2bf(v.z); o.w = f2bf(v.w);
    ((ushort4*)out)[i] = o;
  }
}

// ---------------- GEMM1: qkv = x @ qkv_w^T, fused bias + RoPE ----------------
// A = x_bf16 [32776,768], B = wq_bf16 [2304,768] (bt), out planes [3][32776][768]
__global__ __launch_bounds__(256) void gemm_qkv_rope(
    const unsigned short* __restrict__ A,
    const unsigned short* __restrict__ Bw,
    const float* __restrict__ rope,   // [4096,128] sin||cos
    const float* __restrict__ qb,
    const float* __restrict__ vb,
    unsigned short* __restrict__ qkv)
{
  __shared__ unsigned short L[3*8192];   // 3 bufs x (A 4096 + B 4096 shorts) = 48KB
  const int t    = threadIdx.x;
  const int wave = t >> 6, lane = t & 63;

  // bijective XCD swizzle: nwg=4626, q=578, r=2
  const int o   = blockIdx.x;
  const int xcd = o & 7, loc = o >> 3;
  const int tile = (xcd < 2 ? xcd*579 : 2*579 + (xcd-2)*578) + loc;
  const int m0 = (tile / 18) * 128;
  const int n0 = (tile % 18) * 128;

  const int wr = wave >> 1, wc = wave & 1;
  const int lr = lane & 15, lk = lane >> 4;

  f32x4 acc[4][4];
#pragma unroll
  for (int i = 0; i < 4; ++i)
#pragma unroll
    for (int j = 0; j < 4; ++j) acc[i][j] = (f32x4){0.f,0.f,0.f,0.f};

  const int so0 = (wave*2 + 0) * 1024;   // byte offset within 8KB half
  const int so1 = (wave*2 + 1) * 1024;
  const int f0 = so0 + lane*16, f1 = so1 + lane*16;
  const int r0 = f0 >> 6, cb0 = f0 & 63;
  const int r1 = f1 >> 6, cb1 = f1 & 63;
  const int am0 = min(m0 + r0, M_TOT-1);
  const int am1 = min(m0 + r1, M_TOT-1);
  const unsigned short* ga0 = A + (long)am0*768 + (cb0 >> 1);
  const unsigned short* ga1 = A + (long)am1*768 + (cb1 >> 1);
  const unsigned short* gb0 = Bw + (long)(n0 + r0)*768 + (cb0 >> 1);
  const unsigned short* gb1 = Bw + (long)(n0 + r1)*768 + (cb1 >> 1);

  auto STAGE = [&](int buf, int kk) {
    char* base = (char*)L + buf*16384;
    gload16(ga0 + kk, base + so0);
    gload16(ga1 + kk, base + so1);
    gload16(gb0 + kk, base + 8192 + so0);
    gload16(gb1 + kk, base + 8192 + so1);
  };
  auto COMPUTE = [&](int buf) {
    const unsigned short* Ab = L + buf*8192;
    const unsigned short* Bb = Ab + 4096;
    short8 af[4], bfr[4];
#pragma unroll
    for (int mi = 0; mi < 4; ++mi)
      af[mi] = *(const short8*)(Ab + (wr*64 + mi*16 + lr)*32 + lk*8);
#pragma unroll
    for (int ni = 0; ni < 4; ++ni)
      bfr[ni] = *(const short8*)(Bb + (wc*64 + ni*16 + lr)*32 + lk*8);
#pragma unroll
    for (int mi = 0; mi < 4; ++mi)
#pragma unroll
      for (int ni = 0; ni < 4; ++ni)
        acc[mi][ni] = __builtin_amdgcn_mfma_f32_16x16x32_bf16(af[mi], bfr[ni], acc[mi][ni], 0, 0, 0);
  };

  STAGE(0, 0);
  STAGE(1, 32);
  asm volatile("s_waitcnt vmcnt(4)" ::: "memory");   // buf0 landed
  __builtin_amdgcn_s_barrier();
  __builtin_amdgcn_sched_barrier(0);

  int cur = 0;
  for (int tt = 0; tt < NT-2; ++tt) {
    int stg = cur + 2; if (stg >= 3) stg -= 3;
    STAGE(stg, (tt+2)*32);
    COMPUTE(cur);
    asm volatile("s_waitcnt vmcnt(4)" ::: "memory"); // buf[t+1] landed; t+2 in flight
    __builtin_amdgcn_sched_barrier(0);
    __builtin_amdgcn_s_barrier();
    __builtin_amdgcn_sched_barrier(0);
    cur = (cur + 1 == 3) ? 0 : cur + 1;
  }
  COMPUTE(cur);                                      // t = NT-2
  asm volatile("s_waitcnt vmcnt(0)" ::: "memory");
  __builtin_amdgcn_sched_barrier(0);
  __builtin_amdgcn_s_barrier();
  __builtin_amdgcn_sched_barrier(0);
  cur = (cur + 1 == 3) ? 0 : cur + 1;
  COMPUTE(cur);                                      // t = NT-1

  const int which = n0 / 768;  // block-uniform (768 % 128 == 0)
  unsigned short* plane = qkv + (long)which*M_TOT*768;
#pragma unroll
  for (int mi = 0; mi < 4; ++mi) {
#pragma unroll
    for (int ni = 0; ni < 4; ++ni) {
      const int gc = n0 + wc*64 + ni*16 + lr;
      const int within = gc - which*768;
      const int d = within & 63;
      float bias = 0.f;
      if (which == 0) bias = qb[within];
      else if (which == 2) bias = vb[within];
#pragma unroll
      for (int r = 0; r < 4; ++r) {
        const int gm = m0 + wr*64 + mi*16 + lk*4 + r;
        float v = acc[mi][ni][r] + bias;
        float pair = __shfl_xor(v, 1);   // col d^1 lives in lane^1
        float vo = v;
        if (which < 2) {
          const int ntok = gm % 4097;
          if (ntok > 0 && gm < M_TOT) {
            const float* rp = rope + (long)(ntok - 1)*128 + d;
            const float s = rp[0], c = rp[64];
            const float rot = (d & 1) ? pair : -pair;
            vo = v*c + rot*s;
          }
        }
        if (gm < M_TOT) plane[(long)gm*768 + within] = f2bf(vo);
      }
    }
  }
}

// ---------------- kv partials: kv[b,h] = K^T V over an N-chunk ----------------
__global__ __launch_bounds__(256) void kv_partial_kernel(
    const unsigned short* __restrict__ qkv, float* __restrict__ part)
{
  const int bh = blockIdx.y;            // 0..95
  const int b = bh / 12, h = bh % 12;
  const int chunk = blockIdx.x;         // 0..15
  const int per = (N_ + CHUNKS - 1) / CHUNKS;  // 257
  const int nst = chunk * per;
  const int nen = min(nst + per, N_);
  const unsigned short* Kpl = qkv + (long)M_TOT*768 + ((long)b*N_)*768 + h*64;
  const unsigned short* Vpl = qkv + (long)2*M_TOT*768 + ((long)b*N_)*768 + h*64;
  __shared__ unsigned short Kl[32*64];
  __shared__ unsigned short Vl[32*64];
  const int t = threadIdx.x;
  const int ty = t >> 4, tx = t & 15;
  const int lrow = t >> 3, lpc = t & 7;
  float acc[4][4] = {};
  for (int nb = nst; nb < nen; nb += 32) {
    const int cnt = min(32, nen - nb);
    __syncthreads();
    if (lrow < cnt) {
      *(uint4*)(Kl + lrow*64 + lpc*8) = *(const uint4*)(Kpl + (long)(nb + lrow)*768 + lpc*8);
      *(uint4*)(Vl + lrow*64 + lpc*8) = *(const uint4*)(Vpl + (long)(nb + lrow)*768 + lpc*8);
    }
    __syncthreads();
#pragma unroll 2
    for (int i = 0; i < cnt; ++i) {
      const ushort4 ku = *(const ushort4*)(Kl + i*64 + ty*4);
      const ushort4 vu = *(const ushort4*)(Vl + i*64 + tx*4);
      float kf[4] = {bf2f(ku.x), bf2f(ku.y), bf2f(ku.z), bf2f(ku.w)};
      float vf[4] = {bf2f(vu.x), bf2f(vu.y), bf2f(vu.z), bf2f(vu.w)};
#pragma unroll
      for (int a = 0; a < 4; ++a)
#pragma unroll
        for (int e = 0; e < 4; ++e) acc[a][e] += kf[a]*vf[e];
    }
  }
  float* dst = part + ((long)chunk*96 + bh)*4096 + (ty*4)*64 + tx*4;
#pragma unroll
  for (int a = 0; a < 4; ++a)
#pragma unroll
    for (int e = 0; e < 4; ++e) dst[a*64 + e] = acc[a][e];
}

__global__ __launch_bounds__(256) void kv_reduce_kernel(const float* __restrict__ part,
                                                        float* __restrict__ kvf) {
  const int i = blockIdx.x*256 + threadIdx.x;  // 96*4096 = 393216
  float s = 0.f;
#pragma unroll
  for (int c = 0; c < CHUNKS; ++c) s += part[(long)c*96*4096 + i];
  kvf[i] = s;
}

// ---- McombT[b][c][h*64+d] = sum_e kv[b,h,d,e]*proj_w[c,h*64+e] / (hd*N) ----
__global__ __launch_bounds__(256) void mcomb_kernel(const float* __restrict__ kvf,
                                                    const float* __restrict__ pw,
                                                    unsigned short* __restrict__ McT) {
  const long o = (long)blockIdx.x*256 + threadIdx.x;   // < 8*768*768
  const int j = (int)(o % 768);
  const long t2 = o / 768;
  const int c = (int)(t2 % 768);
  const int b = (int)(t2 / 768);
  const int h = j >> 6, d = j & 63;
  const float* kvp = kvf + ((long)(b*12 + h)*64 + d)*64;
  const float* pwp = pw + (long)c*768 + h*64;
  float s = 0.f;
#pragma unroll 8
  for (int e = 0; e < 64; ++e) s += kvp[e]*pwp[e];
  McT[o] = f2bf(s * (float)(1.0/(64.0*4097.0)));
}

// ---------------- GEMM2: out[b] = Q[b] @ McT[b]^T + proj_b (fp32 out) ----------------
__global__ __launch_bounds__(256) void gemm_final(
    const unsigned short* __restrict__ qkv,   // q plane = first M_TOT*768
    const unsigned short* __restrict__ McT,   // [8,768,768] bf16
    const float* __restrict__ pb,
    float* __restrict__ out)
{
  __shared__ unsigned short L[3*8192];
  const int t    = threadIdx.x;
  const int wave = t >> 6, lane = t & 63;

  // bijective XCD swizzle: nwg=1584 = 8*198 (one batch per XCD)
  const int o   = blockIdx.x;
  const int xcd = o & 7, loc = o >> 3;
  const int tile = xcd*198 + loc;
  const int ct = tile % 6, yt = tile / 6;
  const int b = yt / 33, rt = yt % 33;
  const int n0 = rt * 128;     // token tile start
  const int c0 = ct * 128;     // output-channel tile start

  const int wr = wave >> 1, wc = wave & 1;
  const int lr = lane & 15, lk = lane >> 4;

  f32x4 acc[4][4];
#pragma unroll
  for (int i = 0; i < 4; ++i)
#pragma unroll
    for (int j = 0; j < 4; ++j) acc[i][j] = (f32x4){0.f,0.f,0.f,0.f};

  const int so0 = (wave*2 + 0) * 1024;
  const int so1 = (wave*2 + 1) * 1024;
  const int f0 = so0 + lane*16, f1 = so1 + lane*16;
  const int r0 = f0 >> 6, cb0 = f0 & 63;
  const int r1 = f1 >> 6, cb1 = f1 & 63;
  const int tk0 = min(n0 + r0, N_-1);
  const int tk1 = min(n0 + r1, N_-1);
  const unsigned short* ga0 = qkv + ((long)b*N_ + tk0)*768 + (cb0 >> 1);
  const unsigned short* ga1 = qkv + ((long)b*N_ + tk1)*768 + (cb1 >> 1);
  const unsigned short* Bb = McT + (long)b*768*768;
  const unsigned short* gb0 = Bb + (long)(c0 + r0)*768 + (cb0 >> 1);
  const unsigned short* gb1 = Bb + (long)(c0 + r1)*768 + (cb1 >> 1);

  auto STAGE = [&](int buf, int kk) {
    char* base = (char*)L + buf*16384;
    gload16(ga0 + kk, base + so0);
    gload16(ga1 + kk, base + so1);
    gload16(gb0 + kk, base + 8192 + so0);
    gload16(gb1 + kk, base + 8192 + so1);
  };
  auto COMPUTE = [&](int buf) {
    const unsigned short* Ab = L + buf*8192;
    const unsigned short* Bl = Ab + 4096;
    short8 af[4], bfr[4];
#pragma unroll
    for (int mi = 0; mi < 4; ++mi)
      af[mi] = *(const short8*)(Ab + (wr*64 + mi*16 + lr)*32 + lk*8);
#pragma unroll
    for (int ni = 0; ni < 4; ++ni)
      bfr[ni] = *(const short8*)(Bl + (wc*64 + ni*16 + lr)*32 + lk*8);
#pragma unroll
    for (int mi = 0; mi < 4; ++mi)
#pragma unroll
      for (int ni = 0; ni < 4; ++ni)
        acc[mi][ni] = __builtin_amdgcn_mfma_f32_16x16x32_bf16(af[mi], bfr[ni], acc[mi][ni], 0, 0, 0);
  };

  STAGE(0, 0);
  STAGE(1, 32);
  asm volatile("s_waitcnt vmcnt(4)" ::: "memory");
  __builtin_amdgcn_s_barrier();
  __builtin_amdgcn_sched_barrier(0);

  int cur = 0;
  for (int tt = 0; tt < NT-2; ++tt) {
    int stg = cur + 2; if (stg >= 3) stg -= 3;
    STAGE(stg, (tt+2)*32);
    COMPUTE(cur);
    asm volatile("s_waitcnt vmcnt(4)" ::: "memory");
    __builtin_amdgcn_sched_barrier(0);
    __builtin_amdgcn_s_barrier();
    __builtin_amdgcn_sched_barrier(0);
    cur = (cur + 1 == 3) ? 0 : cur + 1;
  }
  COMPUTE(cur);
  asm volatile("s_waitcnt vmcnt(0)" ::: "memory");
  __builtin_amdgcn_sched_barrier(0);
  __builtin_amdgcn_s_barrier();
  __builtin_amdgcn_sched_barrier(0);
  cur = (cur + 1 == 3) ? 0 : cur + 1;
  COMPUTE(cur);

#pragma unroll
  for (int mi = 0; mi < 4; ++mi) {
#pragma unroll
    for (int ni = 0; ni < 4; ++ni) {
      const int gc = c0 + wc*64 + ni*16 + lr;
      const float bias = pb[gc];
#pragma unroll
      for (int r = 0; r < 4; ++r) {
        const int tok = n0 + wr*64 + mi*16 + lk*4 + r;
        if (tok < N_)
          out[((long)b*N_ + tok)*768 + gc] = acc[mi][ni][r] + bias;
      }
    }
  }
}

extern "C" void kernel_launch(void* const* d_in, const int* in_sizes, int n_in,
                              void* d_out, int out_size, void* d_ws, size_t ws_size,
                              hipStream_t stream) {
  const float* x      = (const float*)d_in[0];
  const float* rope   = (const float*)d_in[1];
  const float* qkv_w  = (const float*)d_in[2];
  const float* q_bias = (const float*)d_in[3];
  const float* v_bias = (const float*)d_in[4];
  const float* proj_w = (const float*)d_in[5];
  const float* proj_b = (const float*)d_in[6];
  float* out = (float*)d_out;

  // workspace layout (region0 reused: x_bf/wq_bf dead after gemm1)
  char* w0 = (char*)d_ws;
  unsigned short* x_bf  = (unsigned short*)w0;                        // 50,343,936 B
  unsigned short* wq_bf = (unsigned short*)(w0 + 50343936);           //  3,538,944 B
  unsigned short* qkv   = (unsigned short*)(w0 + 50343936 + 3538944); // 151,031,808 B (3 planes)
  float*          part  = (float*)w0;                                 // 25,165,824 B (aliases x_bf)
  float*          kvf   = (float*)(w0 + 25165824);                    //  1,572,864 B
  unsigned short* McT   = (unsigned short*)(w0 + 25165824 + 1572864); //  9,437,184 B

  cvt_kernel<<<2048, 256, 0, stream>>>(x, x_bf, (long)M_TOT*768/4);
  cvt_kernel<<<1728, 256, 0, stream>>>(qkv_w, wq_bf, (long)K3*768/4);

  gemm_qkv_rope<<<4626, 256, 0, stream>>>(x_bf, wq_bf, rope, q_bias, v_bias, qkv);

  kv_partial_kernel<<<dim3(CHUNKS, 96), 256, 0, stream>>>(qkv, part);
  kv_reduce_kernel<<<1536, 256, 0, stream>>>(part, kvf);
  mcomb_kernel<<<18432, 256, 0, stream>>>(kvf, proj_w, McT);

  gemm_final<<<1584, 256, 0, stream>>>(qkv, McT, proj_b, out);
}